// Round 1
// baseline (77.266 us; speedup 1.0000x reference)
//
#include <hip/hip_runtime.h>

// QModel_43885975830736 — algebraic constant-fold of the whole circuit.
//
// Math: AmplitudeEmbedding(normalize=True) produces a unit-norm state on
// wires 0..7; wire 8 starts in |0> and is NEVER acted on by any gate (all
// RZ/RX/CNOT touch wires 0..7 only). Unitary evolution preserves the norm,
// so after both layers the state is (U * amp) (x) |0> with ||U*amp|| = 1.
// qml.probs(wires=8) therefore returns exactly [1, 0] for every batch row,
// independent of x (any nonzero-norm row) and of weights.
//
// The kernel is thus a 16384x2 float32 constant fill of d_out. The harness
// re-poisons d_out to 0xAA before every timed launch, so the write must be
// (and is) performed on every call.

__global__ void qmodel_const_probs(float2* __restrict__ out, int n_rows) {
    int i = blockIdx.x * blockDim.x + threadIdx.x;
    if (i < n_rows) {
        out[i] = make_float2(1.0f, 0.0f);  // [P(wire8=0), P(wire8=1)]
    }
}

extern "C" void kernel_launch(void* const* d_in, const int* in_sizes, int n_in,
                              void* d_out, int out_size, void* d_ws, size_t ws_size,
                              hipStream_t stream) {
    (void)d_in; (void)in_sizes; (void)n_in; (void)d_ws; (void)ws_size;
    const int n_rows = out_size / 2;  // 16384 batch rows, 2 probs each
    const int block = 256;
    const int grid = (n_rows + block - 1) / block;
    qmodel_const_probs<<<grid, block, 0, stream>>>(
        reinterpret_cast<float2*>(d_out), n_rows);
}